// Round 3
// baseline (364.117 us; speedup 1.0000x reference)
//
#include <hip/hip_runtime.h>
#include <math.h>

#define BB 1024
#define NN 512
#define MM 256
#define RREG 384                 // rows held in registers (48 per wave)
#define RPT  48                  // register rows per thread (one f4v each)
#define RCACHE (NN - RREG)       // 128 rows left to the cache
#define OUTROW (NN + MM + NN * MM)   // 131840
#define EPS_ADD 1e-16f
#define EPS_COS 1e-8f

typedef float f4v __attribute__((ext_vector_type(4)));

__device__ inline float waveReduceSum(float v) {
#pragma unroll
    for (int off = 32; off > 0; off >>= 1) v += __shfl_xor(v, off);
    return v;
}
__device__ inline float waveReduceMax(float v) {
#pragma unroll
    for (int off = 32; off > 0; off >>= 1) v = fmaxf(v, __shfl_xor(v, off));
    return v;
}

__global__ __launch_bounds__(512, 2) void ntm_memory_kernel(
    const float* __restrict__ memory, const float* __restrict__ key,
    const float* __restrict__ beta, const float* __restrict__ g,
    const float* __restrict__ s, const float* __restrict__ gamma,
    const float* __restrict__ w_prev, const float* __restrict__ e,
    const float* __restrict__ a, float* __restrict__ out) {
    const int b    = blockIdx.x;
    const int t    = threadIdx.x;
    const int lane = t & 63;
    const int wave = t >> 6;          // 0..7

    __shared__ float key_lds[MM];     // key + eps
    __shared__ float sc[NN];          // scores
    __shared__ float wg[NN];          // gated weights (conv input)
    __shared__ float wf[NN];          // final w
    __shared__ float ea_lds[2 * MM];  // [e | a]
    __shared__ float red[8];
    __shared__ float rpart[8][MM];    // r partials

    const float* __restrict__ memb = memory + (size_t)b * NN * MM;
    float* __restrict__ outb       = out + (size_t)b * OUTROW;

    // ---- stage key (+eps), e, a ----
    if (t < MM) {
        key_lds[t]      = key[b * MM + t] + EPS_ADD;
        ea_lds[MM + t]  = a[b * MM + t];
    } else {
        const int i = t - MM;
        ea_lds[i] = e[b * MM + i];
    }
    __syncthreads();

    // ---- key norm (threads 0..255, waves 0..3) ----
    if (t < MM) {
        float kv = key_lds[t];
        float ss = waveReduceSum(kv * kv);
        if (lane == 0) red[wave] = ss;
    }
    __syncthreads();
    const float kn  = fmaxf(sqrtf(red[0] + red[1] + red[2] + red[3]), EPS_COS);
    const float bet = beta[b];
    const float gv  = g[b];
    const float gam = gamma[b];
    const float s0  = s[b * 3 + 0];
    const float s1  = s[b * 3 + 1];
    const float s2  = s[b * 3 + 2];
    __syncthreads();   // red about to be reused

    const int col = lane * 4;
    const f4v kf = *reinterpret_cast<const f4v*>(&key_lds[col]);

    // ---- phase 1a: load 384 rows into registers, compute cosine scores ----
    // wave owns rows n = wave + 8*i; lane owns cols col..col+3.
    f4v tile[RPT];
#pragma unroll
    for (int i = 0; i < RPT; ++i) {
        const int n = wave + 8 * i;
        tile[i] = __builtin_nontemporal_load(
            reinterpret_cast<const f4v*>(memb + n * MM + col));
        const float mx = tile[i].x + EPS_ADD, my = tile[i].y + EPS_ADD;
        const float mz = tile[i].z + EPS_ADD, mw = tile[i].w + EPS_ADD;
        float dot = mx * kf.x + my * kf.y + mz * kf.z + mw * kf.w;
        float ss  = mx * mx + my * my + mz * mz + mw * mw;
#pragma unroll
        for (int off = 32; off > 0; off >>= 1) {
            dot += __shfl_xor(dot, off);
            ss  += __shfl_xor(ss, off);
        }
        if (lane == 0)
            sc[n] = bet * dot / (fmaxf(sqrtf(ss), EPS_COS) * kn);
    }

    // ---- phase 1b: remaining 128 rows, normal (cacheable) loads ----
#pragma unroll
    for (int j = 0; j < RCACHE / 8; ++j) {
        const int n = RREG + wave + 8 * j;
        const f4v mv = *reinterpret_cast<const f4v*>(memb + n * MM + col);
        const float mx = mv.x + EPS_ADD, my = mv.y + EPS_ADD;
        const float mz = mv.z + EPS_ADD, mw = mv.w + EPS_ADD;
        float dot = mx * kf.x + my * kf.y + mz * kf.z + mw * kf.w;
        float ss  = mx * mx + my * my + mz * mz + mw * mw;
#pragma unroll
        for (int off = 32; off > 0; off >>= 1) {
            dot += __shfl_xor(dot, off);
            ss  += __shfl_xor(ss, off);
        }
        if (lane == 0)
            sc[n] = bet * dot / (fmaxf(sqrtf(ss), EPS_COS) * kn);
    }
    __syncthreads();

    // ---- softmax over N=512 (thread t owns element t) ----
    const float v = sc[t];
    {
        float m1 = waveReduceMax(v);
        if (lane == 0) red[wave] = m1;
    }
    __syncthreads();
    float mmax = red[0];
#pragma unroll
    for (int k = 1; k < 8; k++) mmax = fmaxf(mmax, red[k]);
    const float ex = expf(v - mmax);
    __syncthreads();   // done reading red (max)
    {
        float s1w = waveReduceSum(ex);
        if (lane == 0) red[wave] = s1w;
    }
    __syncthreads();
    float esum = 0.f;
#pragma unroll
    for (int k = 0; k < 8; k++) esum += red[k];
    const float w_c = ex / esum;

    // ---- gate + circular conv + sharpen ----
    wg[t] = gv * w_c + (1.f - gv) * w_prev[b * NN + t];
    __syncthreads();
    const float wt = wg[(t + NN - 1) & (NN - 1)] * s0 + wg[t] * s1 +
                     wg[(t + 1) & (NN - 1)] * s2;
    const float wp = powf(wt, gam);
    __syncthreads();   // done reading red (sum)
    {
        float sw = waveReduceSum(wp);
        if (lane == 0) red[wave] = sw;
    }
    __syncthreads();
    float wsum = 0.f;
#pragma unroll
    for (int k = 0; k < 8; k++) wsum += red[k];
    const float wv = wp / (wsum + EPS_ADD);
    wf[t]   = wv;
    outb[t] = wv;      // output w
    __syncthreads();

    // ---- phase 2: read r + write new_mem ----
    {
        const f4v ev = *reinterpret_cast<const f4v*>(&ea_lds[col]);
        const f4v av = *reinterpret_cast<const f4v*>(&ea_lds[MM + col]);
        f4v acc = (f4v)0.f;
        // register-resident rows
#pragma unroll
        for (int i = 0; i < RPT; ++i) {
            const int n = wave + 8 * i;
            const float wn = wf[n];
            const f4v mv = tile[i];
            const f4v nm = mv * (1.f - wn * ev) + wn * av;
            __builtin_nontemporal_store(nm,
                reinterpret_cast<f4v*>(outb + (NN + MM) + n * MM + col));
            acc += wn * mv;
        }
        // cache-resident rows (should hit L2)
#pragma unroll
        for (int j = 0; j < RCACHE / 8; ++j) {
            const int n = RREG + wave + 8 * j;
            const float wn = wf[n];
            const f4v mv = *reinterpret_cast<const f4v*>(memb + n * MM + col);
            const f4v nm = mv * (1.f - wn * ev) + wn * av;
            __builtin_nontemporal_store(nm,
                reinterpret_cast<f4v*>(outb + (NN + MM) + n * MM + col));
            acc += wn * mv;
        }
        *reinterpret_cast<f4v*>(&rpart[wave][col]) = acc;
    }
    __syncthreads();
    if (t < MM) {
        float rsum = 0.f;
#pragma unroll
        for (int k = 0; k < 8; k++) rsum += rpart[k][t];
        outb[NN + t] = rsum;   // output r
    }
}

extern "C" void kernel_launch(void* const* d_in, const int* in_sizes, int n_in,
                              void* d_out, int out_size, void* d_ws, size_t ws_size,
                              hipStream_t stream) {
    const float* memory = (const float*)d_in[0];
    const float* key    = (const float*)d_in[1];
    const float* beta   = (const float*)d_in[2];
    const float* g      = (const float*)d_in[3];
    const float* s      = (const float*)d_in[4];
    const float* gamma  = (const float*)d_in[5];
    const float* w_prev = (const float*)d_in[6];
    const float* e      = (const float*)d_in[7];
    const float* a      = (const float*)d_in[8];
    float* out = (float*)d_out;

    ntm_memory_kernel<<<BB, 512, 0, stream>>>(memory, key, beta, g, s, gamma,
                                              w_prev, e, a, out);
}

// Round 4
// 289.270 us; speedup vs baseline: 1.2587x; 1.2587x over previous
//
#include <hip/hip_runtime.h>
#include <math.h>

#define BB 1024
#define NN 512
#define MM 256
#define OUTROW (NN + MM + NN * MM)   // 131840
#define EPS_ADD 1e-16f
#define EPS_COS 1e-8f
#define G_REG 22                     // register groups per wave (88 rows)
#define G_LDS 3                      // LDS groups per wave (12 rows)
#define G_TOT 32                     // 4-row groups per wave (128 rows)

typedef float f4v __attribute__((ext_vector_type(4)));

__device__ inline float waveReduceSum(float v) {
#pragma unroll
    for (int off = 32; off > 0; off >>= 1) v += __shfl_xor(v, off);
    return v;
}
__device__ inline float waveReduceMax(float v) {
#pragma unroll
    for (int off = 32; off > 0; off >>= 1) v = fmaxf(v, __shfl_xor(v, off));
    return v;
}
__device__ inline f4v shflXor(f4v v, int off) {
    f4v r;
    r.x = __shfl_xor(v.x, off);
    r.y = __shfl_xor(v.y, off);
    r.z = __shfl_xor(v.z, off);
    r.w = __shfl_xor(v.w, off);
    return r;
}

__global__ __launch_bounds__(256, 1) void ntm_memory_kernel(
    const float* __restrict__ memory, const float* __restrict__ key,
    const float* __restrict__ beta, const float* __restrict__ g,
    const float* __restrict__ s, const float* __restrict__ gamma,
    const float* __restrict__ w_prev, const float* __restrict__ e,
    const float* __restrict__ a, float* __restrict__ out) {
    const int b    = blockIdx.x;
    const int t    = threadIdx.x;      // 0..255
    const int lane = t & 63;
    const int wave = t >> 6;           // 0..3
    const int sub  = lane >> 4;        // 0..3  row within 4-row group
    const int sl   = lane & 15;        // 0..15 lanes per row

    __shared__ float key_lds[MM];
    __shared__ float ea_lds[2 * MM];   // [e | a]
    __shared__ float sc[NN];
    __shared__ float wg[NN];
    __shared__ float wf[NN];
    __shared__ float red[4];
    __shared__ float rpart[4][MM];
    __shared__ f4v   TL[4][G_LDS][4][MM / 4];   // 48 KB LDS row tile

    const float* __restrict__ memb = memory + (size_t)b * NN * MM;
    float* __restrict__ outb       = out + (size_t)b * OUTROW;

    // ---- stage key(+eps), e, a ----
    key_lds[t]     = key[b * MM + t] + EPS_ADD;
    ea_lds[t]      = e[b * MM + t];
    ea_lds[MM + t] = a[b * MM + t];
    __syncthreads();

    // ---- key norm ----
    {
        const float kvv = key_lds[t];
        const float ssk = waveReduceSum(kvv * kvv);
        if (lane == 0) red[wave] = ssk;
    }
    __syncthreads();
    const float kn  = fmaxf(sqrtf(red[0] + red[1] + red[2] + red[3]), EPS_COS);
    const float bet = beta[b];
    const float gv  = g[b];
    const float gam = gamma[b];
    const float s0  = s[b * 3 + 0];
    const float s1  = s[b * 3 + 1];
    const float s2  = s[b * 3 + 2];

    const int col0 = sl * 4;
    f4v kf[4];
#pragma unroll
    for (int mc = 0; mc < 4; ++mc)
        kf[mc] = *reinterpret_cast<const f4v*>(&key_lds[mc * 64 + col0]);

    const int row0 = wave * 128 + sub;                    // + 4*grp
    const float* __restrict__ rbase = memb + (size_t)row0 * MM + col0;

    // ---- phase 1: cosine scores; rows land in regs / LDS / cache ----
    f4v tile[G_REG][4];
#pragma unroll
    for (int grp = 0; grp < G_REG; ++grp) {
        const float* rp = rbase + (size_t)(4 * grp) * MM;
        float dot = 0.f, ssq = 0.f;
#pragma unroll
        for (int mc = 0; mc < 4; ++mc) {
            const f4v mv = __builtin_nontemporal_load(
                reinterpret_cast<const f4v*>(rp + mc * 64));
            tile[grp][mc] = mv;
            const float mx = mv.x + EPS_ADD, my = mv.y + EPS_ADD;
            const float mz = mv.z + EPS_ADD, mw = mv.w + EPS_ADD;
            dot += mx * kf[mc].x + my * kf[mc].y + mz * kf[mc].z + mw * kf[mc].w;
            ssq += mx * mx + my * my + mz * mz + mw * mw;
        }
#pragma unroll
        for (int off = 8; off > 0; off >>= 1) {
            dot += __shfl_xor(dot, off);
            ssq += __shfl_xor(ssq, off);
        }
        if (sl == 0)
            sc[row0 + 4 * grp] = bet * dot / (fmaxf(sqrtf(ssq), EPS_COS) * kn);
    }
#pragma unroll
    for (int gl = 0; gl < G_LDS; ++gl) {
        const int grp = G_REG + gl;
        const float* rp = rbase + (size_t)(4 * grp) * MM;
        float dot = 0.f, ssq = 0.f;
#pragma unroll
        for (int mc = 0; mc < 4; ++mc) {
            const f4v mv = __builtin_nontemporal_load(
                reinterpret_cast<const f4v*>(rp + mc * 64));
            TL[wave][gl][sub][mc * 16 + sl] = mv;
            const float mx = mv.x + EPS_ADD, my = mv.y + EPS_ADD;
            const float mz = mv.z + EPS_ADD, mw = mv.w + EPS_ADD;
            dot += mx * kf[mc].x + my * kf[mc].y + mz * kf[mc].z + mw * kf[mc].w;
            ssq += mx * mx + my * my + mz * mz + mw * mw;
        }
#pragma unroll
        for (int off = 8; off > 0; off >>= 1) {
            dot += __shfl_xor(dot, off);
            ssq += __shfl_xor(ssq, off);
        }
        if (sl == 0)
            sc[row0 + 4 * grp] = bet * dot / (fmaxf(sqrtf(ssq), EPS_COS) * kn);
    }
#pragma unroll
    for (int grp = G_REG + G_LDS; grp < G_TOT; ++grp) {
        const float* rp = rbase + (size_t)(4 * grp) * MM;
        float dot = 0.f, ssq = 0.f;
#pragma unroll
        for (int mc = 0; mc < 4; ++mc) {
            const f4v mv = *reinterpret_cast<const f4v*>(rp + mc * 64);  // cacheable
            const float mx = mv.x + EPS_ADD, my = mv.y + EPS_ADD;
            const float mz = mv.z + EPS_ADD, mw = mv.w + EPS_ADD;
            dot += mx * kf[mc].x + my * kf[mc].y + mz * kf[mc].z + mw * kf[mc].w;
            ssq += mx * mx + my * my + mz * mz + mw * mw;
        }
#pragma unroll
        for (int off = 8; off > 0; off >>= 1) {
            dot += __shfl_xor(dot, off);
            ssq += __shfl_xor(ssq, off);
        }
        if (sl == 0)
            sc[row0 + 4 * grp] = bet * dot / (fmaxf(sqrtf(ssq), EPS_COS) * kn);
    }
    __syncthreads();

    // ---- softmax over N=512 (2 elements per thread) ----
    const float v0 = sc[t], v1 = sc[t + 256];
    {
        const float m1 = waveReduceMax(fmaxf(v0, v1));
        if (lane == 0) red[wave] = m1;
    }
    __syncthreads();
    const float mmax = fmaxf(fmaxf(red[0], red[1]), fmaxf(red[2], red[3]));
    const float ex0 = expf(v0 - mmax), ex1 = expf(v1 - mmax);
    __syncthreads();
    {
        const float s1w = waveReduceSum(ex0 + ex1);
        if (lane == 0) red[wave] = s1w;
    }
    __syncthreads();
    const float esum = red[0] + red[1] + red[2] + red[3];

    // ---- gate + circular conv + sharpen ----
    wg[t]       = gv * (ex0 / esum) + (1.f - gv) * w_prev[b * NN + t];
    wg[t + 256] = gv * (ex1 / esum) + (1.f - gv) * w_prev[b * NN + t + 256];
    __syncthreads();
    const float wt0 = wg[(t + NN - 1) & (NN - 1)] * s0 + wg[t] * s1 +
                      wg[(t + 1) & (NN - 1)] * s2;
    const float wt1 = wg[(t + 255) & (NN - 1)] * s0 + wg[t + 256] * s1 +
                      wg[(t + 257) & (NN - 1)] * s2;
    const float wp0 = powf(wt0, gam), wp1 = powf(wt1, gam);
    __syncthreads();
    {
        const float sw = waveReduceSum(wp0 + wp1);
        if (lane == 0) red[wave] = sw;
    }
    __syncthreads();
    const float wsum = red[0] + red[1] + red[2] + red[3] + EPS_ADD;
    const float wv0 = wp0 / wsum, wv1 = wp1 / wsum;
    wf[t]       = wv0;
    wf[t + 256] = wv1;
    outb[t]       = wv0;
    outb[t + 256] = wv1;
    __syncthreads();

    // ---- phase 2: write new_mem + accumulate r ----
    f4v ev[4], av[4], acc[4];
#pragma unroll
    for (int mc = 0; mc < 4; ++mc) {
        ev[mc]  = *reinterpret_cast<const f4v*>(&ea_lds[mc * 64 + col0]);
        av[mc]  = *reinterpret_cast<const f4v*>(&ea_lds[MM + mc * 64 + col0]);
        acc[mc] = (f4v)0.f;
    }
    float* __restrict__ obase = outb + (NN + MM) + (size_t)row0 * MM + col0;
#pragma unroll
    for (int grp = 0; grp < G_REG; ++grp) {
        const float wn = wf[row0 + 4 * grp];
        float* op = obase + (size_t)(4 * grp) * MM;
#pragma unroll
        for (int mc = 0; mc < 4; ++mc) {
            const f4v mv = tile[grp][mc];
            const f4v nm = mv * (1.f - wn * ev[mc]) + wn * av[mc];
            __builtin_nontemporal_store(nm, reinterpret_cast<f4v*>(op + mc * 64));
            acc[mc] += wn * mv;
        }
    }
#pragma unroll
    for (int gl = 0; gl < G_LDS; ++gl) {
        const int grp = G_REG + gl;
        const float wn = wf[row0 + 4 * grp];
        float* op = obase + (size_t)(4 * grp) * MM;
#pragma unroll
        for (int mc = 0; mc < 4; ++mc) {
            const f4v mv = TL[wave][gl][sub][mc * 16 + sl];
            const f4v nm = mv * (1.f - wn * ev[mc]) + wn * av[mc];
            __builtin_nontemporal_store(nm, reinterpret_cast<f4v*>(op + mc * 64));
            acc[mc] += wn * mv;
        }
    }
#pragma unroll
    for (int grp = G_REG + G_LDS; grp < G_TOT; ++grp) {
        const float wn = wf[row0 + 4 * grp];
        const float* rp = rbase + (size_t)(4 * grp) * MM;
        float* op = obase + (size_t)(4 * grp) * MM;
#pragma unroll
        for (int mc = 0; mc < 4; ++mc) {
            const f4v mv = *reinterpret_cast<const f4v*>(rp + mc * 64);  // L3 hit
            const f4v nm = mv * (1.f - wn * ev[mc]) + wn * av[mc];
            __builtin_nontemporal_store(nm, reinterpret_cast<f4v*>(op + mc * 64));
            acc[mc] += wn * mv;
        }
    }
    // reduce r partials across the 4 sub-rows of the wave
#pragma unroll
    for (int mc = 0; mc < 4; ++mc) {
        acc[mc] += shflXor(acc[mc], 16);
        acc[mc] += shflXor(acc[mc], 32);
    }
    if (sub == 0) {
#pragma unroll
        for (int mc = 0; mc < 4; ++mc)
            *reinterpret_cast<f4v*>(&rpart[wave][mc * 64 + col0]) = acc[mc];
    }
    __syncthreads();
    outb[NN + t] = rpart[0][t] + rpart[1][t] + rpart[2][t] + rpart[3][t];
}

extern "C" void kernel_launch(void* const* d_in, const int* in_sizes, int n_in,
                              void* d_out, int out_size, void* d_ws, size_t ws_size,
                              hipStream_t stream) {
    const float* memory = (const float*)d_in[0];
    const float* key    = (const float*)d_in[1];
    const float* beta   = (const float*)d_in[2];
    const float* g      = (const float*)d_in[3];
    const float* s      = (const float*)d_in[4];
    const float* gamma  = (const float*)d_in[5];
    const float* w_prev = (const float*)d_in[6];
    const float* e      = (const float*)d_in[7];
    const float* a      = (const float*)d_in[8];
    float* out = (float*)d_out;

    ntm_memory_kernel<<<BB, 256, 0, stream>>>(memory, key, beta, g, s, gamma,
                                              w_prev, e, a, out);
}

// Round 5
// 285.227 us; speedup vs baseline: 1.2766x; 1.0142x over previous
//
#include <hip/hip_runtime.h>
#include <math.h>

#define BB 1024
#define NN 512
#define MM 256
#define OUTROW (NN + MM + NN * MM)   // 131840
#define EPS_ADD 1e-16f
#define EPS_COS 1e-8f

typedef float f4v __attribute__((ext_vector_type(4)));

__device__ inline float waveReduceSum(float v) {
#pragma unroll
    for (int off = 32; off > 0; off >>= 1) v += __shfl_xor(v, off);
    return v;
}
__device__ inline float waveReduceMax(float v) {
#pragma unroll
    for (int off = 32; off > 0; off >>= 1) v = fmaxf(v, __shfl_xor(v, off));
    return v;
}

__global__ __launch_bounds__(512, 4) void ntm_memory_kernel(
    const float* __restrict__ memory, const float* __restrict__ key,
    const float* __restrict__ beta, const float* __restrict__ g,
    const float* __restrict__ s, const float* __restrict__ gamma,
    const float* __restrict__ w_prev, const float* __restrict__ e,
    const float* __restrict__ a, float* __restrict__ out) {
    const int b    = blockIdx.x;
    const int t    = threadIdx.x;
    const int lane = t & 63;
    const int wave = t >> 6;          // 0..7
    const int sub  = lane >> 4;       // 0..3  (row within 4-row group)
    const int sl   = lane & 15;       // 0..15 (16 lanes share a row)

    __shared__ float key_lds[MM];
    __shared__ float sc[NN];
    __shared__ float wg[NN];
    __shared__ float wf[NN];
    __shared__ float ea_lds[2 * MM];
    __shared__ float red[8];
    __shared__ float rpart[8][MM];

    const float* __restrict__ memb = memory + (size_t)b * NN * MM;
    float* __restrict__ outb       = out + (size_t)b * OUTROW;

    // ---- stage key (+eps), e, a ----
    if (t < MM) {
        key_lds[t]      = key[b * MM + t] + EPS_ADD;
        ea_lds[MM + t]  = a[b * MM + t];
    } else {
        const int i = t - MM;
        ea_lds[i] = e[b * MM + i];
    }
    __syncthreads();

    // ---- key norm ----
    if (t < MM) {
        float kv = key_lds[t];
        float ss = waveReduceSum(kv * kv);
        if (lane == 0) red[wave] = ss;
    }
    __syncthreads();
    const float kn  = fmaxf(sqrtf(red[0] + red[1] + red[2] + red[3]), EPS_COS);
    const float bet = beta[b];
    const float gv  = g[b];
    const float gam = gamma[b];
    const float s0  = s[b * 3 + 0];
    const float s1  = s[b * 3 + 1];
    const float s2  = s[b * 3 + 2];
    __syncthreads();   // red about to be reused

    // ---- phase 1: cosine scores, 16 lanes/row, 2-deep pipelined ----
    {
        f4v kf[4];
#pragma unroll
        for (int mc = 0; mc < 4; mc++)
            kf[mc] = *reinterpret_cast<const f4v*>(&key_lds[mc * 64 + sl * 4]);

        const int rbase = wave * 64 + sub;
        const float* __restrict__ rp0 = memb + (size_t)rbase * MM + sl * 4;

        f4v A[4], B[4];
#pragma unroll
        for (int mc = 0; mc < 4; ++mc)
            A[mc] = *reinterpret_cast<const f4v*>(rp0 + mc * 64);

#pragma unroll
        for (int gi = 0; gi < 16; gi += 2) {
            // prefetch group gi+1 while reducing group gi
            {
                const float* rp = rp0 + (size_t)((gi + 1) * 4) * MM;
#pragma unroll
                for (int mc = 0; mc < 4; ++mc)
                    B[mc] = *reinterpret_cast<const f4v*>(rp + mc * 64);
            }
            {
                float dot = 0.f, ssq = 0.f;
#pragma unroll
                for (int mc = 0; mc < 4; ++mc) {
                    const float mx = A[mc].x + EPS_ADD, my = A[mc].y + EPS_ADD;
                    const float mz = A[mc].z + EPS_ADD, mw = A[mc].w + EPS_ADD;
                    dot += mx * kf[mc].x + my * kf[mc].y + mz * kf[mc].z + mw * kf[mc].w;
                    ssq += mx * mx + my * my + mz * mz + mw * mw;
                }
#pragma unroll
                for (int off = 8; off > 0; off >>= 1) {
                    dot += __shfl_xor(dot, off);
                    ssq += __shfl_xor(ssq, off);
                }
                if (sl == 0)
                    sc[rbase + gi * 4] = bet * dot / (fmaxf(sqrtf(ssq), EPS_COS) * kn);
            }
            // prefetch group gi+2 while reducing group gi+1
            if (gi + 2 < 16) {
                const float* rp = rp0 + (size_t)((gi + 2) * 4) * MM;
#pragma unroll
                for (int mc = 0; mc < 4; ++mc)
                    A[mc] = *reinterpret_cast<const f4v*>(rp + mc * 64);
            }
            {
                float dot = 0.f, ssq = 0.f;
#pragma unroll
                for (int mc = 0; mc < 4; ++mc) {
                    const float mx = B[mc].x + EPS_ADD, my = B[mc].y + EPS_ADD;
                    const float mz = B[mc].z + EPS_ADD, mw = B[mc].w + EPS_ADD;
                    dot += mx * kf[mc].x + my * kf[mc].y + mz * kf[mc].z + mw * kf[mc].w;
                    ssq += mx * mx + my * my + mz * mz + mw * mw;
                }
#pragma unroll
                for (int off = 8; off > 0; off >>= 1) {
                    dot += __shfl_xor(dot, off);
                    ssq += __shfl_xor(ssq, off);
                }
                if (sl == 0)
                    sc[rbase + (gi + 1) * 4] = bet * dot / (fmaxf(sqrtf(ssq), EPS_COS) * kn);
            }
        }
    }
    __syncthreads();

    // ---- softmax over N=512 (thread t owns element t) ----
    const float v = sc[t];
    {
        float m1 = waveReduceMax(v);
        if (lane == 0) red[wave] = m1;
    }
    __syncthreads();
    float mmax = red[0];
#pragma unroll
    for (int k = 1; k < 8; k++) mmax = fmaxf(mmax, red[k]);
    const float ex = expf(v - mmax);
    __syncthreads();
    {
        float s1w = waveReduceSum(ex);
        if (lane == 0) red[wave] = s1w;
    }
    __syncthreads();
    float esum = 0.f;
#pragma unroll
    for (int k = 0; k < 8; k++) esum += red[k];
    const float w_c = ex / esum;

    // ---- gate + circular conv + sharpen ----
    wg[t] = gv * w_c + (1.f - gv) * w_prev[b * NN + t];
    __syncthreads();
    const float wt = wg[(t + NN - 1) & (NN - 1)] * s0 + wg[t] * s1 +
                     wg[(t + 1) & (NN - 1)] * s2;
    const float wp = powf(wt, gam);
    __syncthreads();
    {
        float sw = waveReduceSum(wp);
        if (lane == 0) red[wave] = sw;
    }
    __syncthreads();
    float wsum = 0.f;
#pragma unroll
    for (int k = 0; k < 8; k++) wsum += red[k];
    const float wv = wp / (wsum + EPS_ADD);
    wf[t]   = wv;
    outb[t] = wv;      // output w
    __syncthreads();

    // ---- phase 2: read r + write new_mem, 2-deep pipelined ----
    {
        const int col = lane * 4;
        const f4v ev = *reinterpret_cast<const f4v*>(&ea_lds[col]);
        const f4v av = *reinterpret_cast<const f4v*>(&ea_lds[MM + col]);
        f4v acc = (f4v)0.f;
        float* __restrict__ ob = outb + (NN + MM);

        f4v mA = *reinterpret_cast<const f4v*>(memb + (size_t)wave * MM + col);
        f4v mB;
#pragma unroll
        for (int nb = 0; nb < NN; nb += 16) {
            const int n0 = nb + wave;
            const int n1 = nb + 8 + wave;
            // prefetch iter+1
            mB = *reinterpret_cast<const f4v*>(memb + (size_t)n1 * MM + col);
            // process iter (mA, n0)
            {
                const float wn = wf[n0];
                const f4v nm = mA * (1.f - wn * ev) + wn * av;
                __builtin_nontemporal_store(nm,
                    reinterpret_cast<f4v*>(ob + (size_t)n0 * MM + col));
                acc += wn * mA;
            }
            // prefetch iter+2
            if (nb + 16 < NN)
                mA = *reinterpret_cast<const f4v*>(memb + (size_t)(nb + 16 + wave) * MM + col);
            // process iter+1 (mB, n1)
            {
                const float wn = wf[n1];
                const f4v nm = mB * (1.f - wn * ev) + wn * av;
                __builtin_nontemporal_store(nm,
                    reinterpret_cast<f4v*>(ob + (size_t)n1 * MM + col));
                acc += wn * mB;
            }
        }
        *reinterpret_cast<f4v*>(&rpart[wave][col]) = acc;
    }
    __syncthreads();
    if (t < MM) {
        float rsum = 0.f;
#pragma unroll
        for (int k = 0; k < 8; k++) rsum += rpart[k][t];
        outb[NN + t] = rsum;   // output r
    }
}

extern "C" void kernel_launch(void* const* d_in, const int* in_sizes, int n_in,
                              void* d_out, int out_size, void* d_ws, size_t ws_size,
                              hipStream_t stream) {
    const float* memory = (const float*)d_in[0];
    const float* key    = (const float*)d_in[1];
    const float* beta   = (const float*)d_in[2];
    const float* g      = (const float*)d_in[3];
    const float* s      = (const float*)d_in[4];
    const float* gamma  = (const float*)d_in[5];
    const float* w_prev = (const float*)d_in[6];
    const float* e      = (const float*)d_in[7];
    const float* a      = (const float*)d_in[8];
    float* out = (float*)d_out;

    ntm_memory_kernel<<<BB, 512, 0, stream>>>(memory, key, beta, g, s, gamma,
                                              w_prev, e, a, out);
}

// Round 6
// 209.722 us; speedup vs baseline: 1.7362x; 1.3600x over previous
//
#include <hip/hip_runtime.h>
#include <math.h>

#define BB 1024
#define NN 512
#define MM 256
#define OUTROW (NN + MM + NN * MM)   // 131840
#define EPS_ADD 1e-16f
#define EPS_COS 1e-8f
#define G_REG 11                     // register-resident groups per wave (44 rows)
#define G_TOT 16                     // total 4-row groups per wave (64 rows)

typedef float f4v __attribute__((ext_vector_type(4)));

__device__ inline float waveReduceSum(float v) {
#pragma unroll
    for (int off = 32; off > 0; off >>= 1) v += __shfl_xor(v, off);
    return v;
}
__device__ inline float waveReduceMax(float v) {
#pragma unroll
    for (int off = 32; off > 0; off >>= 1) v = fmaxf(v, __shfl_xor(v, off));
    return v;
}

// load one 4-row group (4 col-chunks of this lane)
__device__ __forceinline__ void ldgrp(f4v (&buf)[4], const float* __restrict__ rp) {
#pragma unroll
    for (int mc = 0; mc < 4; ++mc)
        buf[mc] = *reinterpret_cast<const f4v*>(rp + mc * 64);
}
__device__ __forceinline__ void ldgrp_nt(f4v (&buf)[4], const float* __restrict__ rp) {
#pragma unroll
    for (int mc = 0; mc < 4; ++mc)
        buf[mc] = __builtin_nontemporal_load(reinterpret_cast<const f4v*>(rp + mc * 64));
}

// cosine-score reduce for one group: 16 lanes per row, 8 shuffles
__device__ __forceinline__ void redgrp(const f4v (&buf)[4], const f4v (&kf)[4],
                                       float bet, float kn, float* __restrict__ sc,
                                       int row, int sl) {
    float dot = 0.f, ssq = 0.f;
#pragma unroll
    for (int mc = 0; mc < 4; ++mc) {
        const float mx = buf[mc].x + EPS_ADD, my = buf[mc].y + EPS_ADD;
        const float mz = buf[mc].z + EPS_ADD, mw = buf[mc].w + EPS_ADD;
        dot += mx * kf[mc].x + my * kf[mc].y + mz * kf[mc].z + mw * kf[mc].w;
        ssq += mx * mx + my * my + mz * mz + mw * mw;
    }
#pragma unroll
    for (int off = 8; off > 0; off >>= 1) {
        dot += __shfl_xor(dot, off);
        ssq += __shfl_xor(ssq, off);
    }
    if (sl == 0)
        sc[row] = bet * dot / (fmaxf(sqrtf(ssq), EPS_COS) * kn);
}

// erase/add + r-accumulate + NT-store for one group
__device__ __forceinline__ void procgrp(const f4v (&mvv)[4], float wn,
                                        const f4v (&ev)[4], const f4v (&av)[4],
                                        f4v (&acc)[4], float* __restrict__ op) {
#pragma unroll
    for (int mc = 0; mc < 4; ++mc) {
        const f4v nm = mvv[mc] * (1.f - wn * ev[mc]) + wn * av[mc];
        __builtin_nontemporal_store(nm, reinterpret_cast<f4v*>(op + mc * 64));
        acc[mc] += wn * mvv[mc];
    }
}

__global__ __launch_bounds__(512, 2) void ntm_memory_kernel(
    const float* __restrict__ memory, const float* __restrict__ key,
    const float* __restrict__ beta, const float* __restrict__ g,
    const float* __restrict__ s, const float* __restrict__ gamma,
    const float* __restrict__ w_prev, const float* __restrict__ e,
    const float* __restrict__ a, float* __restrict__ out) {
    const int b    = blockIdx.x;
    const int t    = threadIdx.x;
    const int lane = t & 63;
    const int wave = t >> 6;          // 0..7
    const int sub  = lane >> 4;       // 0..3  row within group
    const int sl   = lane & 15;       // 0..15 lanes per row

    __shared__ float key_lds[MM];
    __shared__ float sc[NN];
    __shared__ float wg[NN];
    __shared__ float wf[NN];
    __shared__ float ea_lds[2 * MM];
    __shared__ float red[8];
    __shared__ float rpart[8][MM];

    const float* __restrict__ memb = memory + (size_t)b * NN * MM;
    float* __restrict__ outb       = out + (size_t)b * OUTROW;

    // ---- stage key (+eps), e, a ----
    if (t < MM) {
        key_lds[t]      = key[b * MM + t] + EPS_ADD;
        ea_lds[MM + t]  = a[b * MM + t];
    } else {
        const int i = t - MM;
        ea_lds[i] = e[b * MM + i];
    }
    __syncthreads();

    // ---- key norm ----
    if (t < MM) {
        float kv = key_lds[t];
        float ss = waveReduceSum(kv * kv);
        if (lane == 0) red[wave] = ss;
    }
    __syncthreads();
    const float kn  = fmaxf(sqrtf(red[0] + red[1] + red[2] + red[3]), EPS_COS);
    const float bet = beta[b];
    const float gv  = g[b];
    const float gam = gamma[b];
    const float s0  = s[b * 3 + 0];
    const float s1  = s[b * 3 + 1];
    const float s2  = s[b * 3 + 2];
    __syncthreads();   // red about to be reused

    const int rowbase = wave * 64 + sub;          // row of group gp = rowbase + 4*gp
    const float* __restrict__ rp0 = memb + (size_t)rowbase * MM + sl * 4;

    f4v kf[4];
#pragma unroll
    for (int mc = 0; mc < 4; ++mc)
        kf[mc] = *reinterpret_cast<const f4v*>(&key_lds[mc * 64 + sl * 4]);

    // ---- phase 1a: fill register tile (44 live-out loads => deep MLP) ----
    f4v tile[G_REG][4];
#pragma unroll
    for (int gp = 0; gp < G_REG; ++gp)
        ldgrp_nt(tile[gp], rp0 + (size_t)(4 * gp) * MM);

    // reduce register groups (compiler staggers vmcnt waits)
#pragma unroll
    for (int gp = 0; gp < G_REG; ++gp)
        redgrp(tile[gp], kf, bet, kn, sc, rowbase + 4 * gp, sl);

    // ---- phase 1b: 5 streaming groups, 2-deep pipelined, cacheable ----
    {
        f4v sA[4], sB[4];
        ldgrp(sA, rp0 + (size_t)(4 * (G_REG + 0)) * MM);
        ldgrp(sB, rp0 + (size_t)(4 * (G_REG + 1)) * MM);
        redgrp(sA, kf, bet, kn, sc, rowbase + 4 * (G_REG + 0), sl);
        ldgrp(sA, rp0 + (size_t)(4 * (G_REG + 2)) * MM);
        redgrp(sB, kf, bet, kn, sc, rowbase + 4 * (G_REG + 1), sl);
        ldgrp(sB, rp0 + (size_t)(4 * (G_REG + 3)) * MM);
        redgrp(sA, kf, bet, kn, sc, rowbase + 4 * (G_REG + 2), sl);
        ldgrp(sA, rp0 + (size_t)(4 * (G_REG + 4)) * MM);
        redgrp(sB, kf, bet, kn, sc, rowbase + 4 * (G_REG + 3), sl);
        redgrp(sA, kf, bet, kn, sc, rowbase + 4 * (G_REG + 4), sl);
    }
    __syncthreads();

    // ---- softmax over N=512 (thread t owns element t) ----
    const float v = sc[t];
    {
        float m1 = waveReduceMax(v);
        if (lane == 0) red[wave] = m1;
    }
    __syncthreads();
    float mmax = red[0];
#pragma unroll
    for (int k = 1; k < 8; k++) mmax = fmaxf(mmax, red[k]);
    const float ex = expf(v - mmax);
    __syncthreads();
    {
        float s1w = waveReduceSum(ex);
        if (lane == 0) red[wave] = s1w;
    }
    __syncthreads();
    float esum = 0.f;
#pragma unroll
    for (int k = 0; k < 8; k++) esum += red[k];
    const float w_c = ex / esum;

    // ---- gate + circular conv + sharpen ----
    wg[t] = gv * w_c + (1.f - gv) * w_prev[b * NN + t];
    __syncthreads();
    const float wt = wg[(t + NN - 1) & (NN - 1)] * s0 + wg[t] * s1 +
                     wg[(t + 1) & (NN - 1)] * s2;
    const float wp = powf(wt, gam);
    __syncthreads();
    {
        float sw = waveReduceSum(wp);
        if (lane == 0) red[wave] = sw;
    }
    __syncthreads();
    float wsum = 0.f;
#pragma unroll
    for (int k = 0; k < 8; k++) wsum += red[k];
    const float wv = wp / (wsum + EPS_ADD);
    wf[t]   = wv;
    outb[t] = wv;      // output w
    __syncthreads();

    // ---- phase 2: new_mem + r ----
    f4v ev[4], av[4], acc[4];
#pragma unroll
    for (int mc = 0; mc < 4; ++mc) {
        ev[mc]  = *reinterpret_cast<const f4v*>(&ea_lds[mc * 64 + sl * 4]);
        av[mc]  = *reinterpret_cast<const f4v*>(&ea_lds[MM + mc * 64 + sl * 4]);
        acc[mc] = (f4v)0.f;
    }
    float* __restrict__ ob0 = outb + (NN + MM) + (size_t)rowbase * MM + sl * 4;

    // register-resident groups: pure compute + NT store
#pragma unroll
    for (int gp = 0; gp < G_REG; ++gp) {
        const float wn = wf[rowbase + 4 * gp];
        procgrp(tile[gp], wn, ev, av, acc, ob0 + (size_t)(4 * gp) * MM);
    }
    // streaming groups: re-read (L2/L3-resident), 2-deep
    {
        f4v sA[4], sB[4];
        ldgrp(sA, rp0 + (size_t)(4 * (G_REG + 0)) * MM);
        ldgrp(sB, rp0 + (size_t)(4 * (G_REG + 1)) * MM);
        procgrp(sA, wf[rowbase + 4 * (G_REG + 0)], ev, av, acc,
                ob0 + (size_t)(4 * (G_REG + 0)) * MM);
        ldgrp(sA, rp0 + (size_t)(4 * (G_REG + 2)) * MM);
        procgrp(sB, wf[rowbase + 4 * (G_REG + 1)], ev, av, acc,
                ob0 + (size_t)(4 * (G_REG + 1)) * MM);
        ldgrp(sB, rp0 + (size_t)(4 * (G_REG + 3)) * MM);
        procgrp(sA, wf[rowbase + 4 * (G_REG + 2)], ev, av, acc,
                ob0 + (size_t)(4 * (G_REG + 2)) * MM);
        ldgrp(sA, rp0 + (size_t)(4 * (G_REG + 4)) * MM);
        procgrp(sB, wf[rowbase + 4 * (G_REG + 3)], ev, av, acc,
                ob0 + (size_t)(4 * (G_REG + 3)) * MM);
        procgrp(sA, wf[rowbase + 4 * (G_REG + 4)], ev, av, acc,
                ob0 + (size_t)(4 * (G_REG + 4)) * MM);
    }

    // reduce r partials across the 4 sub-rows of the wave
#pragma unroll
    for (int mc = 0; mc < 4; ++mc) {
        acc[mc].x += __shfl_xor(acc[mc].x, 16); acc[mc].y += __shfl_xor(acc[mc].y, 16);
        acc[mc].z += __shfl_xor(acc[mc].z, 16); acc[mc].w += __shfl_xor(acc[mc].w, 16);
        acc[mc].x += __shfl_xor(acc[mc].x, 32); acc[mc].y += __shfl_xor(acc[mc].y, 32);
        acc[mc].z += __shfl_xor(acc[mc].z, 32); acc[mc].w += __shfl_xor(acc[mc].w, 32);
    }
    if (sub == 0) {
#pragma unroll
        for (int mc = 0; mc < 4; ++mc)
            *reinterpret_cast<f4v*>(&rpart[wave][mc * 64 + sl * 4]) = acc[mc];
    }
    __syncthreads();
    if (t < MM) {
        float rsum = 0.f;
#pragma unroll
        for (int k = 0; k < 8; k++) rsum += rpart[k][t];
        outb[NN + t] = rsum;   // output r
    }
}

extern "C" void kernel_launch(void* const* d_in, const int* in_sizes, int n_in,
                              void* d_out, int out_size, void* d_ws, size_t ws_size,
                              hipStream_t stream) {
    const float* memory = (const float*)d_in[0];
    const float* key    = (const float*)d_in[1];
    const float* beta   = (const float*)d_in[2];
    const float* g      = (const float*)d_in[3];
    const float* s      = (const float*)d_in[4];
    const float* gamma  = (const float*)d_in[5];
    const float* w_prev = (const float*)d_in[6];
    const float* e      = (const float*)d_in[7];
    const float* a      = (const float*)d_in[8];
    float* out = (float*)d_out;

    ntm_memory_kernel<<<BB, 512, 0, stream>>>(memory, key, beta, g, s, gamma,
                                              w_prev, e, a, out);
}